// Round 1
// baseline (28.859 us; speedup 1.0000x reference)
//
#include <hip/hip_runtime.h>
#include <math.h>

#define KCL 64
#define NPTS 32768
#define NBATCH 8
#define BLOCK 256

// cluster record in LDS: m[9], q[3], const, pad -> 16 floats (64B aligned)
__global__ __launch_bounds__(BLOCK) void point_loss_kernel(
    const float4* __restrict__ pts,        // B*N float4 (x,y,z,sdf)
    const float*  __restrict__ constants,  // B*K
    const float*  __restrict__ scales,     // B*K*3
    const float*  __restrict__ rotations,  // B*K*3
    const float*  __restrict__ centers,    // B*K*3
    float*        __restrict__ out)        // scalar loss (pre-zeroed)
{
    __shared__ float cl[KCL][16];
    __shared__ float wave_sums[BLOCK / 64];

    const int nblk_per_b = NPTS / BLOCK;          // 128
    const int b   = blockIdx.x / nblk_per_b;
    const int nbk = blockIdx.x % nblk_per_b;
    const int tid = threadIdx.x;

    // ---- phase 1: precompute folded cluster params into LDS ----
    if (tid < KCL) {
        const int base = b * KCL + tid;
        const float rx = rotations[base * 3 + 0];
        const float ry = rotations[base * 3 + 1];
        const float rz = rotations[base * 3 + 2];
        float sx, cx, sy, cy, sz, cz;
        __sincosf(rx, &sx, &cx);   // fast path ok for precompute? use accurate:
        sx = sinf(rx); cx = cosf(rx);
        sy = sinf(ry); cy = cosf(ry);
        sz = sinf(rz); cz = cosf(rz);

        // R row-major per reference
        float R[3][3];
        R[0][0] = cz * cy;
        R[0][1] = cz * sy * sx - sz * cx;
        R[0][2] = cz * sy * cx + sz * sx;
        R[1][0] = sz * cy;
        R[1][1] = sz * sy * sx + cz * cx;
        R[1][2] = sz * sy * cx - cz * sx;
        R[2][0] = -sy;
        R[2][1] = cy * sx;
        R[2][2] = cy * cx;

        const float is0 = 1.0f / scales[base * 3 + 0];
        const float is1 = 1.0f / scales[base * 3 + 1];
        const float is2 = 1.0f / scales[base * 3 + 2];
        const float inv[3] = {is0, is1, is2};

        const float c0 = centers[base * 3 + 0];
        const float c1 = centers[base * 3 + 1];
        const float c2 = centers[base * 3 + 2];

        // local_i = sum_j R[j][i] * diff_j ; fold 1/scale_i into row i
        #pragma unroll
        for (int i = 0; i < 3; ++i) {
            const float m0 = R[0][i] * inv[i];
            const float m1 = R[1][i] * inv[i];
            const float m2 = R[2][i] * inv[i];
            cl[tid][i * 3 + 0] = m0;
            cl[tid][i * 3 + 1] = m1;
            cl[tid][i * 3 + 2] = m2;
            cl[tid][9 + i] = m0 * c0 + m1 * c1 + m2 * c2;  // q_i = (M c)_i
        }
        cl[tid][12] = constants[base];
    }
    __syncthreads();

    // ---- phase 2: per-point accumulation ----
    const int n = nbk * BLOCK + tid;
    const float4 p = pts[b * NPTS + n];
    const float px = p.x, py = p.y, pz = p.z;

    float sdf = 0.0f;
    #pragma unroll 8
    for (int k = 0; k < KCL; ++k) {
        const float* c = cl[k];
        float vx = fmaf(c[0], px, fmaf(c[1], py, fmaf(c[2], pz, -c[9])));
        float vy = fmaf(c[3], px, fmaf(c[4], py, fmaf(c[5], pz, -c[10])));
        float vz = fmaf(c[6], px, fmaf(c[7], py, fmaf(c[8], pz, -c[11])));
        float d2 = fmaf(vx, vx, fmaf(vy, vy, vz * vz));
        sdf = fmaf(c[12], __expf(-0.5f * d2), sdf);
    }

    // loss term
    const float class_gt = (p.w > 0.0f) ? 1.0f : 0.0f;
    const float z = 100.0f * (sdf + 0.07f);            // SOFT*(sdf - LEVEL_SET)
    const float class_pred = 1.0f / (1.0f + expf(-z));
    const float w = class_gt + 10.0f * (1.0f - class_gt);
    const float d = class_gt - class_pred;
    float term = w * d * d;

    // ---- reduction: wave (64) shuffle, then cross-wave in LDS ----
    #pragma unroll
    for (int off = 32; off > 0; off >>= 1)
        term += __shfl_down(term, off, 64);

    const int wave = tid >> 6;
    const int lane = tid & 63;
    if (lane == 0) wave_sums[wave] = term;
    __syncthreads();

    if (tid == 0) {
        float s = 0.0f;
        #pragma unroll
        for (int i = 0; i < BLOCK / 64; ++i) s += wave_sums[i];
        atomicAdd(out, s * (1.0f / (NBATCH * (float)NPTS)));
    }
}

extern "C" void kernel_launch(void* const* d_in, const int* in_sizes, int n_in,
                              void* d_out, int out_size, void* d_ws, size_t ws_size,
                              hipStream_t stream) {
    const float4* pts       = (const float4*)d_in[0];
    const float*  constants = (const float*)d_in[1];
    const float*  scales    = (const float*)d_in[2];
    const float*  rotations = (const float*)d_in[3];
    const float*  centers   = (const float*)d_in[4];
    float* out = (float*)d_out;

    hipMemsetAsync(out, 0, sizeof(float), stream);

    const int nblocks = NBATCH * (NPTS / BLOCK);   // 1024
    point_loss_kernel<<<nblocks, BLOCK, 0, stream>>>(
        pts, constants, scales, rotations, centers, out);
}